// Round 1
// 672.874 us; speedup vs baseline: 1.0955x; 1.0955x over previous
//
#include <hip/hip_runtime.h>

// NaN-aware conv2d. FP32 I/O, bf16 MFMA compute.
// x[16,128,128,128] NCHW f32, kernel[256,128,3,3] OIHW f32, bias[256] f32
// -> out[16,256,128,128] f32.  STRIDE=1 PAD=1 THRESHOLD=0.5.
//
// out = conv(A~,K) + bias, A~ = x with NaN -> patch_mean of destination patch.
// Implicit GEMM: M=262144 (b,oh,ow), N=256 (oc), K=1152 (c,kh,kw).
//
// R1 changes vs prior 738us version (theory: VALU-staging-bound, nt-duplication):
//  - tile M=64 x N=256 (4 waves): removes oc-half duplication of A sel2 staging
//  - B staged via global_load_lds from PRE-SWIZZLED W2 (zero VALU B staging)
//  - XOR-swizzled LDS (byte ^= (row&7)<<4), unpadded 128B rows: conflict-free b128
//  - double-buffered 1-barrier-per-step pipeline (stage(next) before compute(cur))

typedef __attribute__((ext_vector_type(8))) short bf16x8;
typedef __attribute__((ext_vector_type(4))) float f32x4;

#define HH 128
#define WW 128
#define CC 128

__device__ __forceinline__ unsigned short f2bf(float f) {
    union { float f; unsigned int i; } v; v.f = f;
    unsigned int u = v.i;
    if ((u & 0x7FFFFFFFu) > 0x7F800000u) return (unsigned short)((u >> 16) | 0x0040u);
    unsigned int r = u + 0x7FFFu + ((u >> 16) & 1u);  // RNE
    return (unsigned short)(r >> 16);
}
__device__ __forceinline__ unsigned int sel2(unsigned int v, unsigned int pmu) {
    // per-16-bit bf16 lane: isnan ? pm : value
    unsigned int lo = v & 0xFFFFu, hi = v >> 16;
    if ((lo & 0x7FFFu) > 0x7F80u) lo = pmu;
    if ((hi & 0x7FFFu) > 0x7F80u) hi = pmu;
    return lo | (hi << 16);
}
__device__ __forceinline__ void gl16(const void* g, void* l) {
    __builtin_amdgcn_global_load_lds(
        (const __attribute__((address_space(1))) unsigned int*)g,
        (__attribute__((address_space(3))) unsigned int*)l, 16, 0, 0);
}

// ---- kernel 1: NCHW f32 -> NHWC bf16 (group-local) + per-pixel channel NaN stats --
__global__ void k_transpose_stats(const float* __restrict__ x,
                                  unsigned short* __restrict__ xT,
                                  float* __restrict__ cnt,
                                  float* __restrict__ sum, int b0) {
    int bh = blockIdx.x;              // bl*128 + h
    int bl = bh >> 7, h = bh & 127;
    int b = b0 + bl;
    int w = threadIdx.x;              // 0..127
    const float* xp = x + ((long)b * CC * HH * WW) + h * WW + w;
    unsigned short* xTp = xT + ((((long)bh << 7) + w) << 7);
    int cntv = 0; float sumv = 0.f;
    for (int c8 = 0; c8 < 16; ++c8) {
        unsigned short s8[8];
        #pragma unroll
        for (int j = 0; j < 8; ++j) {
            float fv = xp[(long)(c8 * 8 + j) * (HH * WW)];
            unsigned int bits = __float_as_uint(fv);
            if ((bits & 0x7FFFFFFFu) > 0x7F800000u) { cntv++; s8[j] = 0x7FC0u; }
            else { sumv += fv; s8[j] = f2bf(fv); }
        }
        uint4 p;
        p.x = (unsigned)s8[0] | ((unsigned)s8[1] << 16);
        p.y = (unsigned)s8[2] | ((unsigned)s8[3] << 16);
        p.z = (unsigned)s8[4] | ((unsigned)s8[5] << 16);
        p.w = (unsigned)s8[6] | ((unsigned)s8[7] << 16);
        *(uint4*)(xTp + c8 * 8) = p;
    }
    cnt[(bh << 7) + w] = (float)cntv;
    sum[(bh << 7) + w] = sumv;
}

// ---- kernel 2: 3x3 window of per-pixel stats -> patch_mean bf16 -------------------
__global__ void k_patchmean(const float* __restrict__ cnt, const float* __restrict__ sum,
                            unsigned short* __restrict__ pm) {
    int idx = blockIdx.x * 256 + threadIdx.x;     // (bl*128+oh)*128+ow
    int ow = idx & 127, oh = (idx >> 7) & 127, bl = idx >> 14;
    float nc = 0.f, vs = 0.f;
    #pragma unroll
    for (int kh = 0; kh < 3; ++kh) {
        int ih = oh + kh - 1; if (ih < 0 || ih >= HH) continue;
        #pragma unroll
        for (int kw = 0; kw < 3; ++kw) {
            int iw = ow + kw - 1; if (iw < 0 || iw >= WW) continue;
            int p = (((bl << 7) + ih) << 7) + iw;
            nc += cnt[p]; vs += sum[p];
        }
    }
    float pmv = vs / fmaxf(1152.f - nc, 1.f);
    unsigned short r = f2bf(pmv);
    if (nc >= 576.f) r = 0x7FC0u;                 // bad patch (statistically impossible here)
    pm[idx] = r;
}

// ---- kernel 3: kernel f32 OIHW -> W2 bf16, PRE-SWIZZLED LDS image -----------------
// Layout: [khw][half][oc=r][s] with s the swizzled short-col:
//   logical c = half*64 + (s ^ ((r&7)<<3))
// so that a linear global_load_lds copy of a 32KB slab lands XOR-swizzled in LDS.
__global__ void k_w2(const float* __restrict__ krn, unsigned short* __restrict__ W2) {
    int e = blockIdx.x * 256 + threadIdx.x;       // 294912 total
    int s = e & 63;
    int r = (e >> 6) & 255;                       // oc
    int half = (e >> 14) & 1;
    int khw = e >> 15;
    int c = (half << 6) | (s ^ ((r & 7) << 3));
    W2[e] = f2bf(krn[(r * 128 + c) * 9 + khw]);
}

// ---- kernel 4: implicit-GEMM MFMA conv ------------------------------------------
// block 256 = 4 waves, tile 64 pixels x 256 oc; wave = 64x64 = 4x4 of 16x16x32.
// 18 K-steps of K=64 ((kh,kw) x c-half), double-buffered, 1 barrier/step.
__global__ __launch_bounds__(256) void k_gemm(
    const unsigned short* __restrict__ xT, const unsigned short* __restrict__ pm,
    const unsigned short* __restrict__ W2, const float* __restrict__ bias,
    float* __restrict__ out, int b0) {
    __shared__ __align__(16) unsigned short lA[2][64 * 64];    // 2 x 8KB
    __shared__ __align__(16) unsigned short lB[2][256 * 64];   // 2 x 32KB

    int bid = blockIdx.x;
    int ow0 = (bid & 1) << 6;         // which 64-pixel half of the row
    int oh  = (bid >> 1) & 127;
    int bl  = bid >> 8;
    int b   = b0 + bl;

    int tid = threadIdx.x;
    int lane = tid & 63, wave = tid >> 6;         // wave = oc-slice index (0..3)
    int l15 = lane & 15, quad = lane >> 4;

    // A staging role: 4 threads per row, 16 shorts (2 x uint4) each
    int arow = tid >> 2, apart = tid & 3;
    int ow = ow0 + arow;
    unsigned int pmr = pm[(((bl << 7) + oh) << 7) + ow];   // dest-patch mean (bf16)

    // B staging: wave w DMAs its own 8KB slice (rows w*64..w*64+63), 8 x 1KB
    const char* w2base = (const char*)W2;
    int bgoff = (wave << 13) + (lane << 4);   // per-lane global offset within slab
    int bloff = (wave << 13);                 // wave-uniform LDS base

    f32x4 acc[4][4];
    #pragma unroll
    for (int i = 0; i < 4; ++i)
        #pragma unroll
        for (int j = 0; j < 4; ++j) acc[i][j] = (f32x4)0.f;

    auto STAGE = [&](unsigned short* la, unsigned short* lb, int s) {
        int khw = s >> 1, c0 = (s & 1) << 6;
        int kh = khw / 3, kw = khw - kh * 3;
        int ih = oh + kh - 1, iw = ow + kw - 1;
        // B: 8 x global_load_lds (W2 slab is pre-swizzled; dest linear)
        const char* bsrc = w2base + (s << 15) + bgoff;
        char* ldst = (char*)lb + bloff;
        #pragma unroll
        for (int i = 0; i < 8; ++i)
            gl16(bsrc + (i << 10), ldst + (i << 10));
        // A: 2 x uint4, NaN->pm blend, swizzled ds_write (exact zeros off-edge)
        uint4 v0 = {0u,0u,0u,0u}, v1 = {0u,0u,0u,0u};
        if ((unsigned)ih < 128u && (unsigned)iw < 128u) {
            const unsigned short* ap =
                xT + ((((long)((bl << 7) + ih) << 7) + iw) << 7) + c0 + (apart << 4);
            v0 = *(const uint4*)ap;
            v1 = *(const uint4*)(ap + 8);
        }
        uint4 r0, r1;
        r0.x = sel2(v0.x, pmr); r0.y = sel2(v0.y, pmr);
        r0.z = sel2(v0.z, pmr); r0.w = sel2(v0.w, pmr);
        r1.x = sel2(v1.x, pmr); r1.y = sel2(v1.y, pmr);
        r1.z = sel2(v1.z, pmr); r1.w = sel2(v1.w, pmr);
        char* lar = (char*)la + (arow << 7);
        int sw = (arow & 7) << 4;
        *(uint4*)(lar + (((apart << 5) | 0)  ^ sw)) = r0;
        *(uint4*)(lar + (((apart << 5) | 16) ^ sw)) = r1;
    };

    auto COMPUTE = [&](const unsigned short* la, const unsigned short* lb) {
        int swr = (l15 & 7) << 4;
        #pragma unroll
        for (int ks = 0; ks < 2; ++ks) {
            bf16x8 af[4], bfr[4];
            int cb = ((ks << 6) | (quad << 4)) ^ swr;
            #pragma unroll
            for (int mi = 0; mi < 4; ++mi) {
                int r = (mi << 4) + l15;
                af[mi] = *(const bf16x8*)((const char*)la + (r << 7) + cb);
            }
            #pragma unroll
            for (int ni = 0; ni < 4; ++ni) {
                int r = (wave << 6) + (ni << 4) + l15;
                bfr[ni] = *(const bf16x8*)((const char*)lb + (r << 7) + cb);
            }
            #pragma unroll
            for (int mi = 0; mi < 4; ++mi)
                #pragma unroll
                for (int ni = 0; ni < 4; ++ni)
                    acc[mi][ni] = __builtin_amdgcn_mfma_f32_16x16x32_bf16(
                        af[mi], bfr[ni], acc[mi][ni], 0, 0, 0);
        }
    };

    STAGE(lA[0], lB[0], 0);
    __syncthreads();
    for (int s = 0; s < 18; s += 2) {
        STAGE(lA[1], lB[1], s + 1);       // issue next-step loads BEFORE compute
        COMPUTE(lA[0], lB[0]);
        __syncthreads();                  // one vmcnt(0)+barrier per step
        if (s + 2 < 18) STAGE(lA[0], lB[0], s + 2);
        COMPUTE(lA[1], lB[1]);
        __syncthreads();
    }

    // epilogue: C/D layout col(n)=lane&15 -> oc, row(m)=quad*4+reg -> ow. fp32 out.
    #pragma unroll
    for (int ni = 0; ni < 4; ++ni) {
        int oc = (wave << 6) + (ni << 4) + l15;
        float bv = bias[oc];
        float* op = out + ((long)((b << 8) + oc) * 128 + oh) * 128 + ow0;
        #pragma unroll
        for (int mi = 0; mi < 4; ++mi) {
            int og = (mi << 4) + (quad << 2);
            float4 o;
            o.x = acc[mi][ni][0] + bv;
            o.y = acc[mi][ni][1] + bv;
            o.z = acc[mi][ni][2] + bv;
            o.w = acc[mi][ni][3] + bv;
            *(float4*)(op + og) = o;
        }
    }
}

extern "C" void kernel_launch(void* const* d_in, const int* in_sizes, int n_in,
                              void* d_out, int out_size, void* d_ws, size_t ws_size,
                              hipStream_t stream) {
    const float* x    = (const float*)d_in[0];
    const float* krn  = (const float*)d_in[1];
    const float* bias = (const float*)d_in[2];
    float* out = (float*)d_out;

    // pick batch-group size G so scratch fits ws_size
    const size_t W2_BYTES = 294912ull * 2;                 // 576 KB bf16
    int G = 16;
    while (G > 1) {
        size_t need = W2_BYTES + 256
                    + (size_t)G * (16384ull * 128 * 2)      // xT: G*4MB bf16
                    + (size_t)G * (16384ull * 4) * 2        // cnt+sum: G*128KB
                    + (size_t)G * (16384ull * 2)            // pm: G*32KB
                    + 1024;
        if (need <= ws_size) break;
        G >>= 1;
    }

    char* ws = (char*)d_ws;
    size_t off = 0;
    auto carve = [&](size_t bytes) { char* p = ws + off; off += (bytes + 255) & ~255ull; return p; };
    unsigned short* W2  = (unsigned short*)carve(W2_BYTES);
    unsigned short* xT  = (unsigned short*)carve((size_t)G * 16384 * 128 * 2);
    float*          cnt = (float*)carve((size_t)G * 16384 * 4);
    float*          sum = (float*)carve((size_t)G * 16384 * 4);
    unsigned short* pm  = (unsigned short*)carve((size_t)G * 16384 * 2);

    k_w2<<<dim3(1152), dim3(256), 0, stream>>>(krn, W2);
    for (int b0 = 0; b0 < 16; b0 += G) {
        k_transpose_stats<<<dim3(G * 128), dim3(128), 0, stream>>>(x, xT, cnt, sum, b0);
        k_patchmean<<<dim3(G * 64), dim3(256), 0, stream>>>(cnt, sum, pm);
        k_gemm<<<dim3(G * 256), dim3(256), 0, stream>>>(xT, pm, W2, bias, out, b0);
    }
}

// Round 2
// 657.377 us; speedup vs baseline: 1.1213x; 1.0236x over previous
//
#include <hip/hip_runtime.h>

// NaN-aware conv2d. FP32 I/O, bf16 MFMA compute.
// x[16,128,128,128] NCHW f32, kernel[256,128,3,3] OIHW f32, bias[256] f32
// -> out[16,256,128,128] f32.  STRIDE=1 PAD=1 THRESHOLD=0.5.
//
// out = conv(A~,K) + bias, A~ = x with NaN -> patch_mean of destination patch.
// Implicit GEMM: M=262144 (b,oh,ow), N=256 (oc), K=1152 (c,kh,kw).
//
// R2: counted-vmcnt pipeline (T3/T4). Tile 128x256, 8 waves, 18 K-steps of 64.
//  - raw s_barrier + manual s_waitcnt; vmcnt never drained to 0 in steady state
//  - B(s+1) DMA (global_load_lds, pre-swizzled W2) in flight across COMPUTE(s)
//  - A reg-loads prefetched 2 steps deep; sel2 NaN->pm blend on the reg path
//  - k_transpose_stats: LDS-transposed coalesced xT writes

typedef __attribute__((ext_vector_type(8))) short bf16x8;
typedef __attribute__((ext_vector_type(4))) float f32x4;

#define HH 128
#define WW 128
#define CC 128

__device__ __forceinline__ unsigned short f2bf(float f) {
    union { float f; unsigned int i; } v; v.f = f;
    unsigned int u = v.i;
    if ((u & 0x7FFFFFFFu) > 0x7F800000u) return (unsigned short)((u >> 16) | 0x0040u);
    unsigned int r = u + 0x7FFFu + ((u >> 16) & 1u);  // RNE
    return (unsigned short)(r >> 16);
}
__device__ __forceinline__ unsigned int sel2(unsigned int v, unsigned int pmu) {
    // per-16-bit bf16 lane: isnan ? pm : value
    unsigned int lo = v & 0xFFFFu, hi = v >> 16;
    if ((lo & 0x7FFFu) > 0x7F80u) lo = pmu;
    if ((hi & 0x7FFFu) > 0x7F80u) hi = pmu;
    return lo | (hi << 16);
}
__device__ __forceinline__ void gl16(const void* g, void* l) {
    __builtin_amdgcn_global_load_lds(
        (const __attribute__((address_space(1))) unsigned int*)g,
        (__attribute__((address_space(3))) unsigned int*)l, 16, 0, 0);
}
#define SBAR() __builtin_amdgcn_sched_barrier(0)

// ---- kernel 1: NCHW f32 -> NHWC bf16 (group-local) + per-pixel channel NaN stats --
__global__ void k_transpose_stats(const float* __restrict__ x,
                                  unsigned short* __restrict__ xT,
                                  float* __restrict__ cnt,
                                  float* __restrict__ sum, int b0) {
    __shared__ __align__(16) unsigned short ls[128][136];   // 272B rows: 16B-aligned
    int bh = blockIdx.x;              // bl*128 + h
    int bl = bh >> 7, h = bh & 127;
    int b = b0 + bl;
    int w = threadIdx.x;              // 0..127
    const float* xp = x + ((long)b * CC * HH * WW) + h * WW + w;
    int cntv = 0; float sumv = 0.f;
    for (int c8 = 0; c8 < 16; ++c8) {
        unsigned short s8[8];
        #pragma unroll
        for (int j = 0; j < 8; ++j) {
            float fv = xp[(long)(c8 * 8 + j) * (HH * WW)];
            unsigned int bits = __float_as_uint(fv);
            if ((bits & 0x7FFFFFFFu) > 0x7F800000u) { cntv++; s8[j] = 0x7FC0u; }
            else { sumv += fv; s8[j] = f2bf(fv); }
        }
        uint4 p;
        p.x = (unsigned)s8[0] | ((unsigned)s8[1] << 16);
        p.y = (unsigned)s8[2] | ((unsigned)s8[3] << 16);
        p.z = (unsigned)s8[4] | ((unsigned)s8[5] << 16);
        p.w = (unsigned)s8[6] | ((unsigned)s8[7] << 16);
        *(uint4*)&ls[w][c8 * 8] = p;
    }
    cnt[(bh << 7) + w] = (float)cntv;
    sum[(bh << 7) + w] = sumv;
    __syncthreads();
    // coalesced write-back: 16 rounds, each wave writes 1KB contiguous
    unsigned short* xb = xT + ((long)bh << 14);
    int ch = w & 15, pw = w >> 4;
    #pragma unroll
    for (int r = 0; r < 16; ++r) {
        int p = (r << 3) + pw;
        *(uint4*)(xb + (p << 7) + (ch << 3)) = *(const uint4*)&ls[p][ch << 3];
    }
}

// ---- kernel 2: 3x3 window of per-pixel stats -> patch_mean bf16 -------------------
__global__ void k_patchmean(const float* __restrict__ cnt, const float* __restrict__ sum,
                            unsigned short* __restrict__ pm) {
    int idx = blockIdx.x * 256 + threadIdx.x;     // (bl*128+oh)*128+ow
    int ow = idx & 127, oh = (idx >> 7) & 127, bl = idx >> 14;
    float nc = 0.f, vs = 0.f;
    #pragma unroll
    for (int kh = 0; kh < 3; ++kh) {
        int ih = oh + kh - 1; if (ih < 0 || ih >= HH) continue;
        #pragma unroll
        for (int kw = 0; kw < 3; ++kw) {
            int iw = ow + kw - 1; if (iw < 0 || iw >= WW) continue;
            int p = (((bl << 7) + ih) << 7) + iw;
            nc += cnt[p]; vs += sum[p];
        }
    }
    float pmv = vs / fmaxf(1152.f - nc, 1.f);
    unsigned short r = f2bf(pmv);
    if (nc >= 576.f) r = 0x7FC0u;                 // bad patch (statistically impossible here)
    pm[idx] = r;
}

// ---- kernel 3: kernel f32 OIHW -> W2 bf16, PRE-SWIZZLED LDS image -----------------
// Layout: [khw][half][oc=r][s] with s the swizzled short-col:
//   logical c = half*64 + (s ^ ((r&7)<<3))
// so a linear global_load_lds copy of a 32KB slab lands XOR-swizzled in LDS.
__global__ void k_w2(const float* __restrict__ krn, unsigned short* __restrict__ W2) {
    int e = blockIdx.x * 256 + threadIdx.x;       // 294912 total
    int s = e & 63;
    int r = (e >> 6) & 255;                       // oc
    int half = (e >> 14) & 1;
    int khw = e >> 15;
    int c = (half << 6) | (s ^ ((r & 7) << 3));
    W2[e] = f2bf(krn[(r * 128 + c) * 9 + khw]);
}

// ---- kernel 4: implicit-GEMM MFMA conv, counted-vmcnt pipeline --------------------
// block 512 = 8 waves (2M x 4N), tile 128 pixels x 256 oc; wave 64x64 = 4x4 of 16x16x32.
__global__ __launch_bounds__(512, 2) void k_gemm(
    const unsigned short* __restrict__ xT, const unsigned short* __restrict__ pm,
    const unsigned short* __restrict__ W2, const float* __restrict__ bias,
    float* __restrict__ out, int b0) {
    __shared__ __align__(16) unsigned short lA[2][128 * 64];   // 2 x 16KB
    __shared__ __align__(16) unsigned short lB[2][256 * 64];   // 2 x 32KB

    int bid = blockIdx.x;
    int oh = bid & 127, bl = bid >> 7;
    int b = b0 + bl;

    int tid = threadIdx.x;
    int lane = tid & 63, wave = tid >> 6;
    int wm = wave >> 2, wn = wave & 3;            // 2M x 4N wave grid
    int l15 = lane & 15, quad = lane >> 4;

    // A staging role: 4 threads per pixel row, 32B (2 x uint4) each
    int arow = tid >> 2, apart = tid & 3;         // arow = ow (0..127)
    unsigned int pmr = pm[(((bl << 7) + oh) << 7) + arow];

    // B staging: 4 DMA instrs per wave, 1KB each, linear (W2 pre-swizzled)
    const char* w2base = (const char*)W2;
    int bsrcoff = (wave << 10) + (lane << 4);
    int bdstoff = (wave << 10);

    f32x4 acc[4][4];
    #pragma unroll
    for (int i = 0; i < 4; ++i)
        #pragma unroll
        for (int j = 0; j < 4; ++j) acc[i][j] = (f32x4)0.f;

    auto issueB = [&](int s, unsigned short* lbbuf) {
        const char* src = w2base + ((long)s << 15) + bsrcoff;
        char* dst = (char*)lbbuf + bdstoff;
        #pragma unroll
        for (int i = 0; i < 4; ++i)
            gl16(src + (i << 13), dst + (i << 13));
    };
    auto loadA = [&](int s, uint4& v0, uint4& v1, unsigned& msk) {
        int khw = s >> 1, c0s = (s & 1) << 6;
        int kh = khw / 3, kw = khw - kh * 3;
        int ih = oh + kh - 1, iw = arow + kw - 1;
        bool valid = ((unsigned)ih < 128u) && ((unsigned)iw < 128u);
        int ihc = ih < 0 ? 0 : (ih > 127 ? 127 : ih);
        int iwc = iw < 0 ? 0 : (iw > 127 ? 127 : iw);
        const uint4* ap = (const uint4*)(xT +
            ((((long)((bl << 7) + ihc) << 7) + iwc) << 7) + c0s + (apart << 4));
        v0 = ap[0];
        v1 = ap[1];
        msk = valid ? 0xFFFFFFFFu : 0u;
    };
    auto stageA = [&](uint4 v0, uint4 v1, unsigned msk, unsigned short* la) {
        v0.x &= msk; v0.y &= msk; v0.z &= msk; v0.w &= msk;
        v1.x &= msk; v1.y &= msk; v1.z &= msk; v1.w &= msk;
        uint4 r0, r1;
        r0.x = sel2(v0.x, pmr); r0.y = sel2(v0.y, pmr);
        r0.z = sel2(v0.z, pmr); r0.w = sel2(v0.w, pmr);
        r1.x = sel2(v1.x, pmr); r1.y = sel2(v1.y, pmr);
        r1.z = sel2(v1.z, pmr); r1.w = sel2(v1.w, pmr);
        char* lar = (char*)la + (arow << 7);
        int sw = (arow & 7) << 4;
        *(uint4*)(lar + (((apart << 5) | 0)  ^ sw)) = r0;
        *(uint4*)(lar + (((apart << 5) | 16) ^ sw)) = r1;
    };
    auto COMPUTE = [&](const unsigned short* la, const unsigned short* lb) {
        int swr = (l15 & 7) << 4;
        #pragma unroll
        for (int ks = 0; ks < 2; ++ks) {
            bf16x8 af[4], bfr[4];
            int cb = ((ks << 6) | (quad << 4)) ^ swr;
            #pragma unroll
            for (int mi = 0; mi < 4; ++mi) {
                int r = (wm << 6) + (mi << 4) + l15;
                af[mi] = *(const bf16x8*)((const char*)la + (r << 7) + cb);
            }
            #pragma unroll
            for (int ni = 0; ni < 4; ++ni) {
                int r = (wn << 6) + (ni << 4) + l15;
                bfr[ni] = *(const bf16x8*)((const char*)lb + (r << 7) + cb);
            }
            #pragma unroll
            for (int mi = 0; mi < 4; ++mi)
                #pragma unroll
                for (int ni = 0; ni < 4; ++ni)
                    acc[mi][ni] = __builtin_amdgcn_mfma_f32_16x16x32_bf16(
                        af[mi], bfr[ni], acc[mi][ni], 0, 0, 0);
        }
    };

    uint4 av0[2], av1[2]; unsigned am[2];

    // ---- prologue: B(0), A(0), A(1) in flight; publish lA[0]+lB[0] ----
    issueB(0, lB[0]); SBAR();
    loadA(0, av0[0], av1[0], am[0]); SBAR();
    loadA(1, av0[1], av1[1], am[1]); SBAR();
    asm volatile("s_waitcnt vmcnt(2)" ::: "memory");   // B(0)+A(0) done, A(1) flying
    SBAR();
    stageA(av0[0], av1[0], am[0], lA[0]);
    asm volatile("s_waitcnt lgkmcnt(0)" ::: "memory");
    SBAR();
    __builtin_amdgcn_s_barrier();
    SBAR();

    // ---- main loop: 18 K-steps, fully unrolled, counted waits ----
    #pragma unroll
    for (int s = 0; s < 18; ++s) {
        const int cur = s & 1, nxt = cur ^ 1;
        if (s < 17) { issueB(s + 1, lB[nxt]); SBAR(); }
        if (s < 16) { loadA(s + 2, av0[cur], av1[cur], am[cur]); SBAR(); }
        // wait for A(s+1) (leaves B(s+1)=4 and A(s+2)=2 in flight)
        if (s < 16)      { asm volatile("s_waitcnt vmcnt(6)" ::: "memory"); }
        else if (s == 16){ asm volatile("s_waitcnt vmcnt(4)" ::: "memory"); }
        SBAR();
        if (s < 17) stageA(av0[nxt], av1[nxt], am[nxt], lA[nxt]);
        COMPUTE(lA[cur], lB[cur]);
        if (s < 17) {
            // B(s+1) must be resident before the barrier that precedes COMPUTE(s+1)
            if (s < 16) { asm volatile("s_waitcnt vmcnt(2) lgkmcnt(0)" ::: "memory"); }
            else        { asm volatile("s_waitcnt vmcnt(0) lgkmcnt(0)" ::: "memory"); }
            SBAR();
            __builtin_amdgcn_s_barrier();
            SBAR();
        }
    }

    // epilogue: C/D layout col(n)=lane&15 -> oc, row(m)=quad*4+reg -> ow. fp32 out.
    #pragma unroll
    for (int ni = 0; ni < 4; ++ni) {
        int oc = (wn << 6) + (ni << 4) + l15;
        float bv = bias[oc];
        float* op = out + ((long)((b << 8) + oc) * 128 + oh) * 128;
        #pragma unroll
        for (int mi = 0; mi < 4; ++mi) {
            int ow0 = (wm << 6) + (mi << 4) + (quad << 2);
            float4 o;
            o.x = acc[mi][ni][0] + bv;
            o.y = acc[mi][ni][1] + bv;
            o.z = acc[mi][ni][2] + bv;
            o.w = acc[mi][ni][3] + bv;
            *(float4*)(op + ow0) = o;
        }
    }
}

extern "C" void kernel_launch(void* const* d_in, const int* in_sizes, int n_in,
                              void* d_out, int out_size, void* d_ws, size_t ws_size,
                              hipStream_t stream) {
    const float* x    = (const float*)d_in[0];
    const float* krn  = (const float*)d_in[1];
    const float* bias = (const float*)d_in[2];
    float* out = (float*)d_out;

    // pick batch-group size G so scratch fits ws_size
    const size_t W2_BYTES = 294912ull * 2;                 // 576 KB bf16
    int G = 16;
    while (G > 1) {
        size_t need = W2_BYTES + 256
                    + (size_t)G * (16384ull * 128 * 2)      // xT: G*4MB bf16
                    + (size_t)G * (16384ull * 4) * 2        // cnt+sum: G*128KB
                    + (size_t)G * (16384ull * 2)            // pm: G*32KB
                    + 1024;
        if (need <= ws_size) break;
        G >>= 1;
    }

    char* ws = (char*)d_ws;
    size_t off = 0;
    auto carve = [&](size_t bytes) { char* p = ws + off; off += (bytes + 255) & ~255ull; return p; };
    unsigned short* W2  = (unsigned short*)carve(W2_BYTES);
    unsigned short* xT  = (unsigned short*)carve((size_t)G * 16384 * 128 * 2);
    float*          cnt = (float*)carve((size_t)G * 16384 * 4);
    float*          sum = (float*)carve((size_t)G * 16384 * 4);
    unsigned short* pm  = (unsigned short*)carve((size_t)G * 16384 * 2);

    k_w2<<<dim3(1152), dim3(256), 0, stream>>>(krn, W2);
    for (int b0 = 0; b0 < 16; b0 += G) {
        k_transpose_stats<<<dim3(G * 128), dim3(128), 0, stream>>>(x, xT, cnt, sum, b0);
        k_patchmean<<<dim3(G * 64), dim3(256), 0, stream>>>(cnt, sum, pm);
        k_gemm<<<dim3(G * 128), dim3(512), 0, stream>>>(xT, pm, W2, bias, out, b0);
    }
}

// Round 3
// 619.457 us; speedup vs baseline: 1.1900x; 1.0612x over previous
//
#include <hip/hip_runtime.h>

// NaN-aware conv2d. FP32 I/O, bf16 MFMA compute.
// x[16,128,128,128] NCHW f32, kernel[256,128,3,3] OIHW f32, bias[256] f32
// -> out[16,256,128,128] f32.  STRIDE=1 PAD=1 THRESHOLD=0.5.
//
// out = conv(A~,K) + bias, A~ = x with NaN -> patch_mean of destination patch.
// Implicit GEMM: M=262144 (b,oh,ow), N=256 (oc), K=1152 (c,kh,kw).
//
// R3: occupancy-first. R1 vs R2 showed step time (8400cyc) is latency-bound at
// 8 waves/CU regardless of schedule. Now: tile 64x256, BK=32, 256 threads,
// LDS 40KB -> 4 independent blocks/CU (16 waves, 4 barrier groups).
//  - chunk-XOR swizzle (c2 ^ ((row>>1)&3)) for 64B LDS rows, A and B paths
//  - B via global_load_lds from pre-swizzled W2; counted-vmcnt pipeline kept

typedef __attribute__((ext_vector_type(8))) short bf16x8;
typedef __attribute__((ext_vector_type(4))) float f32x4;

#define HH 128
#define WW 128
#define CC 128

__device__ __forceinline__ unsigned short f2bf(float f) {
    union { float f; unsigned int i; } v; v.f = f;
    unsigned int u = v.i;
    if ((u & 0x7FFFFFFFu) > 0x7F800000u) return (unsigned short)((u >> 16) | 0x0040u);
    unsigned int r = u + 0x7FFFu + ((u >> 16) & 1u);  // RNE
    return (unsigned short)(r >> 16);
}
__device__ __forceinline__ unsigned int sel2(unsigned int v, unsigned int pmu) {
    // per-16-bit bf16 lane: isnan ? pm : value
    unsigned int lo = v & 0xFFFFu, hi = v >> 16;
    if ((lo & 0x7FFFu) > 0x7F80u) lo = pmu;
    if ((hi & 0x7FFFu) > 0x7F80u) hi = pmu;
    return lo | (hi << 16);
}
__device__ __forceinline__ void gl16(const void* g, void* l) {
    __builtin_amdgcn_global_load_lds(
        (const __attribute__((address_space(1))) unsigned int*)g,
        (__attribute__((address_space(3))) unsigned int*)l, 16, 0, 0);
}
#define SBAR() __builtin_amdgcn_sched_barrier(0)

// ---- kernel 1: NCHW f32 -> NHWC bf16 (group-local) + per-pixel channel NaN stats --
__global__ void k_transpose_stats(const float* __restrict__ x,
                                  unsigned short* __restrict__ xT,
                                  float* __restrict__ cnt,
                                  float* __restrict__ sum, int b0) {
    __shared__ __align__(16) unsigned short ls[128][136];   // 272B rows: 16B-aligned
    int bh = blockIdx.x;              // bl*128 + h
    int bl = bh >> 7, h = bh & 127;
    int b = b0 + bl;
    int w = threadIdx.x;              // 0..127
    const float* xp = x + ((long)b * CC * HH * WW) + h * WW + w;
    int cntv = 0; float sumv = 0.f;
    for (int c8 = 0; c8 < 16; ++c8) {
        unsigned short s8[8];
        #pragma unroll
        for (int j = 0; j < 8; ++j) {
            float fv = xp[(long)(c8 * 8 + j) * (HH * WW)];
            unsigned int bits = __float_as_uint(fv);
            if ((bits & 0x7FFFFFFFu) > 0x7F800000u) { cntv++; s8[j] = 0x7FC0u; }
            else { sumv += fv; s8[j] = f2bf(fv); }
        }
        uint4 p;
        p.x = (unsigned)s8[0] | ((unsigned)s8[1] << 16);
        p.y = (unsigned)s8[2] | ((unsigned)s8[3] << 16);
        p.z = (unsigned)s8[4] | ((unsigned)s8[5] << 16);
        p.w = (unsigned)s8[6] | ((unsigned)s8[7] << 16);
        *(uint4*)&ls[w][c8 * 8] = p;
    }
    cnt[(bh << 7) + w] = (float)cntv;
    sum[(bh << 7) + w] = sumv;
    __syncthreads();
    // coalesced write-back: 16 rounds, each wave writes 1KB contiguous
    unsigned short* xb = xT + ((long)bh << 14);
    int ch = w & 15, pw = w >> 4;
    #pragma unroll
    for (int r = 0; r < 16; ++r) {
        int p = (r << 3) + pw;
        *(uint4*)(xb + (p << 7) + (ch << 3)) = *(const uint4*)&ls[p][ch << 3];
    }
}

// ---- kernel 2: 3x3 window of per-pixel stats -> patch_mean bf16 -------------------
__global__ void k_patchmean(const float* __restrict__ cnt, const float* __restrict__ sum,
                            unsigned short* __restrict__ pm) {
    int idx = blockIdx.x * 256 + threadIdx.x;     // (bl*128+oh)*128+ow
    int ow = idx & 127, oh = (idx >> 7) & 127, bl = idx >> 14;
    float nc = 0.f, vs = 0.f;
    #pragma unroll
    for (int kh = 0; kh < 3; ++kh) {
        int ih = oh + kh - 1; if (ih < 0 || ih >= HH) continue;
        #pragma unroll
        for (int kw = 0; kw < 3; ++kw) {
            int iw = ow + kw - 1; if (iw < 0 || iw >= WW) continue;
            int p = (((bl << 7) + ih) << 7) + iw;
            nc += cnt[p]; vs += sum[p];
        }
    }
    float pmv = vs / fmaxf(1152.f - nc, 1.f);
    unsigned short r = f2bf(pmv);
    if (nc >= 576.f) r = 0x7FC0u;                 // bad patch (statistically impossible here)
    pm[idx] = r;
}

// ---- kernel 3: kernel f32 OIHW -> W2 bf16, PRE-SWIZZLED LDS image -----------------
// Slab s = khw*4 + kq: 16KB = [oc=r 0..255][32 ch] with 16B chunks XOR-swizzled:
//   stored chunk c2 holds logical ch = kq*32 + (c2 ^ ((r>>1)&3))*8 + j
// so a linear global_load_lds copy lands swizzled in LDS.
__global__ void k_w2(const float* __restrict__ krn, unsigned short* __restrict__ W2) {
    int e = blockIdx.x * 256 + threadIdx.x;       // 294912 total
    int j = e & 7;
    int c2 = (e >> 3) & 3;
    int r = (e >> 5) & 255;                       // oc
    int kq = (e >> 13) & 3;
    int khw = e >> 15;
    int c = (kq << 5) + ((c2 ^ ((r >> 1) & 3)) << 3) + j;
    W2[e] = f2bf(krn[(r * 128 + c) * 9 + khw]);
}

// ---- kernel 4: implicit-GEMM MFMA conv, 4 blocks/CU, counted-vmcnt ---------------
// block 256 = 4 waves (N-slices), tile 64 pixels x 256 oc; wave 64x64 = 4x4 of 16x16x32.
// 36 K-steps of 32 ((kh,kw) x c-quarter), double-buffered.
__global__ __launch_bounds__(256, 4) void k_gemm(
    const unsigned short* __restrict__ xT, const unsigned short* __restrict__ pm,
    const unsigned short* __restrict__ W2, const float* __restrict__ bias,
    float* __restrict__ out, int b0) {
    __shared__ __align__(16) unsigned short lA[2][64 * 32];    // 2 x 4KB
    __shared__ __align__(16) unsigned short lB[2][256 * 32];   // 2 x 16KB

    int bid = blockIdx.x;
    int ow0 = (bid & 1) << 6;         // 64-pixel half of the row
    int oh  = (bid >> 1) & 127;
    int bl  = bid >> 8;
    int b   = b0 + bl;

    int tid = threadIdx.x;
    int lane = tid & 63, wave = tid >> 6;         // wave = oc-slice (0..3)
    int l15 = lane & 15, quad = lane >> 4;

    // A staging role: 4 threads per pixel row, 16B (1 uint4) each
    int arow = tid >> 2, apart = tid & 3;         // arow 0..63
    int ow = ow0 + arow;
    unsigned int pmr = pm[(((bl << 7) + oh) << 7) + ow];

    // B staging: 4 DMA instrs per wave, 1KB each, linear (W2 pre-swizzled)
    const char* w2base = (const char*)W2;
    int bsrcoff = (wave << 12) + (lane << 4);
    int bdstoff = (wave << 12);

    f32x4 acc[4][4];
    #pragma unroll
    for (int i = 0; i < 4; ++i)
        #pragma unroll
        for (int j = 0; j < 4; ++j) acc[i][j] = (f32x4)0.f;

    auto issueB = [&](int s, unsigned short* lbbuf) {
        const char* src = w2base + ((long)s << 14) + bsrcoff;
        char* dst = (char*)lbbuf + bdstoff;
        #pragma unroll
        for (int i = 0; i < 4; ++i)
            gl16(src + (i << 10), dst + (i << 10));
    };
    auto loadA = [&](int s, uint4& v, unsigned& msk) {
        int khw = s >> 2, kq = s & 3;
        int kh = khw / 3, kw = khw - kh * 3;
        int ih = oh + kh - 1, iw = ow + kw - 1;
        bool valid = ((unsigned)ih < 128u) && ((unsigned)iw < 128u);
        int ihc = ih < 0 ? 0 : (ih > 127 ? 127 : ih);
        int iwc = iw < 0 ? 0 : (iw > 127 ? 127 : iw);
        v = *(const uint4*)(xT + ((((long)((bl << 7) + ihc) << 7) + iwc) << 7)
                            + (kq << 5) + (apart << 3));
        msk = valid ? 0xFFFFFFFFu : 0u;
    };
    auto stageA = [&](uint4 v, unsigned msk, unsigned short* la) {
        v.x &= msk; v.y &= msk; v.z &= msk; v.w &= msk;
        uint4 r0;
        r0.x = sel2(v.x, pmr); r0.y = sel2(v.y, pmr);
        r0.z = sel2(v.z, pmr); r0.w = sel2(v.w, pmr);
        char* dst = (char*)la + (arow << 6) + ((apart ^ ((arow >> 1) & 3)) << 4);
        *(uint4*)dst = r0;
    };
    auto COMPUTE = [&](const unsigned short* la, const unsigned short* lb) {
        int cb = (quad ^ ((l15 >> 1) & 3)) << 4;
        bf16x8 af[4], bfr[4];
        #pragma unroll
        for (int mi = 0; mi < 4; ++mi)
            af[mi] = *(const bf16x8*)((const char*)la + (((mi << 4) + l15) << 6) + cb);
        #pragma unroll
        for (int ni = 0; ni < 4; ++ni)
            bfr[ni] = *(const bf16x8*)((const char*)lb +
                       (((wave << 6) + (ni << 4) + l15) << 6) + cb);
        #pragma unroll
        for (int mi = 0; mi < 4; ++mi)
            #pragma unroll
            for (int ni = 0; ni < 4; ++ni)
                acc[mi][ni] = __builtin_amdgcn_mfma_f32_16x16x32_bf16(
                    af[mi], bfr[ni], acc[mi][ni], 0, 0, 0);
    };

    uint4 av[2]; unsigned am[2];

    // ---- prologue: B(0), A(0), A(1) in flight; publish lA[0]+lB[0] ----
    issueB(0, lB[0]); SBAR();
    loadA(0, av[0], am[0]); SBAR();
    loadA(1, av[1], am[1]); SBAR();
    asm volatile("s_waitcnt vmcnt(1)" ::: "memory");   // B(0)+A(0) done, A(1) flying
    SBAR();
    stageA(av[0], am[0], lA[0]);
    asm volatile("s_waitcnt lgkmcnt(0)" ::: "memory");
    SBAR();
    __builtin_amdgcn_s_barrier();
    SBAR();

    // ---- main loop: 36 K-steps, fully unrolled, counted waits ----
    #pragma unroll
    for (int s = 0; s < 36; ++s) {
        const int cur = s & 1, nxt = cur ^ 1;
        if (s < 35) { issueB(s + 1, lB[nxt]); SBAR(); }
        if (s < 34) { loadA(s + 2, av[cur], am[cur]); SBAR(); }
        // wait for A(s+1) (leaves B(s+1)=4 and A(s+2)=1 in flight)
        if (s < 34)      { asm volatile("s_waitcnt vmcnt(5)" ::: "memory"); }
        else if (s == 34){ asm volatile("s_waitcnt vmcnt(4)" ::: "memory"); }
        SBAR();
        if (s < 35) stageA(av[nxt], am[nxt], lA[nxt]);
        COMPUTE(lA[cur], lB[cur]);
        if (s < 35) {
            // B(s+1) resident before the barrier preceding COMPUTE(s+1)
            if (s < 34) { asm volatile("s_waitcnt vmcnt(1) lgkmcnt(0)" ::: "memory"); }
            else        { asm volatile("s_waitcnt vmcnt(0) lgkmcnt(0)" ::: "memory"); }
            SBAR();
            __builtin_amdgcn_s_barrier();
            SBAR();
        }
    }

    // epilogue: C/D layout col(n)=lane&15 -> oc, row(m)=quad*4+reg -> ow. fp32 out.
    #pragma unroll
    for (int ni = 0; ni < 4; ++ni) {
        int oc = (wave << 6) + (ni << 4) + l15;
        float bv = bias[oc];
        float* op = out + ((long)((b << 8) + oc) * 128 + oh) * 128 + ow0;
        #pragma unroll
        for (int mi = 0; mi < 4; ++mi) {
            int og = (mi << 4) + (quad << 2);
            float4 o;
            o.x = acc[mi][ni][0] + bv;
            o.y = acc[mi][ni][1] + bv;
            o.z = acc[mi][ni][2] + bv;
            o.w = acc[mi][ni][3] + bv;
            *(float4*)(op + og) = o;
        }
    }
}

extern "C" void kernel_launch(void* const* d_in, const int* in_sizes, int n_in,
                              void* d_out, int out_size, void* d_ws, size_t ws_size,
                              hipStream_t stream) {
    const float* x    = (const float*)d_in[0];
    const float* krn  = (const float*)d_in[1];
    const float* bias = (const float*)d_in[2];
    float* out = (float*)d_out;

    // pick batch-group size G so scratch fits ws_size
    const size_t W2_BYTES = 294912ull * 2;                 // 576 KB bf16
    int G = 16;
    while (G > 1) {
        size_t need = W2_BYTES + 256
                    + (size_t)G * (16384ull * 128 * 2)      // xT: G*4MB bf16
                    + (size_t)G * (16384ull * 4) * 2        // cnt+sum: G*128KB
                    + (size_t)G * (16384ull * 2)            // pm: G*32KB
                    + 1024;
        if (need <= ws_size) break;
        G >>= 1;
    }

    char* ws = (char*)d_ws;
    size_t off = 0;
    auto carve = [&](size_t bytes) { char* p = ws + off; off += (bytes + 255) & ~255ull; return p; };
    unsigned short* W2  = (unsigned short*)carve(W2_BYTES);
    unsigned short* xT  = (unsigned short*)carve((size_t)G * 16384 * 128 * 2);
    float*          cnt = (float*)carve((size_t)G * 16384 * 4);
    float*          sum = (float*)carve((size_t)G * 16384 * 4);
    unsigned short* pm  = (unsigned short*)carve((size_t)G * 16384 * 2);

    k_w2<<<dim3(1152), dim3(256), 0, stream>>>(krn, W2);
    for (int b0 = 0; b0 < 16; b0 += G) {
        k_transpose_stats<<<dim3(G * 128), dim3(128), 0, stream>>>(x, xT, cnt, sum, b0);
        k_patchmean<<<dim3(G * 64), dim3(256), 0, stream>>>(cnt, sum, pm);
        k_gemm<<<dim3(G * 256), dim3(256), 0, stream>>>(xT, pm, W2, bias, out, b0);
    }
}